// Round 1
// baseline (10583.897 us; speedup 1.0000x reference)
//
#include <hip/hip_runtime.h>

#define TT 1024
#define BB 64
#define FF 256
#define HH 512

// ---------------------------------------------------------------------------
// Kernel 1: i_n = x @ W_ih^T + b_ih   ->  written into io (= d_out), later
// overwritten in-place by the recurrence with h_t.
// M = T*B = 65536, N = H = 512, K = F = 256. Tiles: 32(M) x 64(N) x 64(K).
// ---------------------------------------------------------------------------
__global__ __launch_bounds__(256) void in_gemm(
    const float* __restrict__ x, const float* __restrict__ Wih,
    const float* __restrict__ bih, float* __restrict__ io)
{
    __shared__ float xs[32][68];   // pad 68: conflict-free + 16B-aligned rows
    __shared__ float wst[64][68];  // transposed W tile: wst[k][j]

    const int bid = blockIdx.x;
    const int rb = bid >> 3, cb = bid & 7;
    const int m0 = rb * 32, n0 = cb * 64;
    const int t  = threadIdx.x;
    const int ti = t >> 4, tj = t & 15;

    float acc[2][4] = {{0.f,0.f,0.f,0.f},{0.f,0.f,0.f,0.f}};

    for (int k0 = 0; k0 < FF; k0 += 64) {
        {   // x tile: 32x64 floats, 8 per thread
            int flat = t * 8;
            int row = flat >> 6, col = flat & 63;
            const float* src = &x[(size_t)(m0 + row) * FF + k0 + col];
            float4 a = *(const float4*)&src[0];
            float4 b = *(const float4*)&src[4];
            *(float4*)&xs[row][col]     = a;
            *(float4*)&xs[row][col + 4] = b;
        }
        {   // W tile transposed: 64x64 floats, 16 per thread
            int j  = t >> 2;          // 0..63
            int kk = (t & 3) * 16;    // 0,16,32,48
            const float* src = &Wih[(size_t)(n0 + j) * FF + k0 + kk];
            #pragma unroll
            for (int q = 0; q < 4; ++q) {
                float4 v = *(const float4*)&src[q * 4];
                wst[kk + q*4 + 0][j] = v.x;
                wst[kk + q*4 + 1][j] = v.y;
                wst[kk + q*4 + 2][j] = v.z;
                wst[kk + q*4 + 3][j] = v.w;
            }
        }
        __syncthreads();
        #pragma unroll
        for (int k = 0; k < 64; k += 4) {
            float4 xa = *(const float4*)&xs[ti][k];
            float4 xb = *(const float4*)&xs[ti + 16][k];
            #pragma unroll
            for (int q = 0; q < 4; ++q) {
                float4 wv = *(const float4*)&wst[k + q][tj * 4];
                float xav = (&xa.x)[q], xbv = (&xb.x)[q];
                acc[0][0] = fmaf(xav, wv.x, acc[0][0]);
                acc[0][1] = fmaf(xav, wv.y, acc[0][1]);
                acc[0][2] = fmaf(xav, wv.z, acc[0][2]);
                acc[0][3] = fmaf(xav, wv.w, acc[0][3]);
                acc[1][0] = fmaf(xbv, wv.x, acc[1][0]);
                acc[1][1] = fmaf(xbv, wv.y, acc[1][1]);
                acc[1][2] = fmaf(xbv, wv.z, acc[1][2]);
                acc[1][3] = fmaf(xbv, wv.w, acc[1][3]);
            }
        }
        __syncthreads();
    }

    float4 bv = *(const float4*)&bih[n0 + tj * 4];
    float4 r0 = make_float4(acc[0][0]+bv.x, acc[0][1]+bv.y, acc[0][2]+bv.z, acc[0][3]+bv.w);
    float4 r1 = make_float4(acc[1][0]+bv.x, acc[1][1]+bv.y, acc[1][2]+bv.z, acc[1][3]+bv.w);
    *(float4*)&io[(size_t)(m0 + ti)      * HH + n0 + tj * 4] = r0;
    *(float4*)&io[(size_t)(m0 + ti + 16) * HH + n0 + tj * 4] = r1;
}

// ---------------------------------------------------------------------------
// Kernel 2: persistent recurrence.
// Grid: 256 WGs = 8 row-slices (s) x 32 batch-groups (g, 2 batches each).
// blockIdx = s*32 + g  ->  a group's 8 WGs share blockIdx mod 8 (same XCD
// under round-robin dispatch; perf heuristic only).
// Each WG: W_hh rows [64s,64s+64) (f) and [512+64s,...) (n) in REGISTERS:
//   wave w (16 waves) owns k-slice [32w,32w+32); lane l owns row 64s+l.
//   64 VGPRs of W per thread, persistent for all 1024 steps.
// Per step: stage h (2 batches) to LDS -> broadcast ds_reads + 128 FMA/thread
// -> cross-wave LDS reduce -> 128 threads do gate math, write h to io (over
// the i_n value they just consumed) and to the ping-pong hbuf -> 8-WG
// monotonic atomic barrier (agent scope).
// Occupancy: 1024 thr, <=128 VGPR (launch_bounds), 20KB LDS -> exactly
// 1 WG/CU (VGPR-limited), 256 WGs on 256 CUs -> all co-resident.
// ---------------------------------------------------------------------------
__global__ __launch_bounds__(1024, 4) void mgu_rec(
    const float* __restrict__ Whh, const float* __restrict__ bhh,
    float* __restrict__ io, float* __restrict__ hbuf,
    unsigned int* __restrict__ bar)
{
    const int bid = blockIdx.x;
    const int s   = bid >> 5;     // row slice 0..7
    const int g   = bid & 31;     // batch group 0..31
    const int c0  = g * 2;        // first batch of this group
    const int tid = threadIdx.x;
    const int w   = tid >> 6;     // wave 0..15 -> k-slice
    const int l   = tid & 63;     // lane -> row offset within slice

    __shared__ float hst[2][HH];      // staged h for the 2 batches (4 KB)
    __shared__ float red[16][4][64];  // per-wave partials (16 KB)

    // --- load persistent W registers ---
    float Wf[32], Wn[32];
    {
        const float* pf = &Whh[(size_t)(s * 64 + l) * HH + w * 32];
        const float* pn = &Whh[(size_t)(512 + s * 64 + l) * HH + w * 32];
        #pragma unroll
        for (int q = 0; q < 8; ++q) {
            float4 a = *(const float4*)&pf[q * 4];
            Wf[q*4+0] = a.x; Wf[q*4+1] = a.y; Wf[q*4+2] = a.z; Wf[q*4+3] = a.w;
            float4 b = *(const float4*)&pn[q * 4];
            Wn[q*4+0] = b.x; Wn[q*4+1] = b.y; Wn[q*4+2] = b.z; Wn[q*4+3] = b.w;
        }
    }

    float bfv = 0.f, bnv = 0.f;
    if (tid < 128) {
        int ej = tid & 63;
        bfv = bhh[s * 64 + ej];
        bnv = bhh[512 + s * 64 + ej];
    }

    unsigned int* mybar = &bar[g * 32];  // 128B-spaced line per group

    for (int t = 0; t < TT; ++t) {
        const int p = t & 1;

        // stage h (2 batches x 512) into LDS; 1 float/thread, coalesced
        {
            int c = tid >> 9;       // 0..1
            int k = tid & 511;
            hst[c][k] = hbuf[(size_t)p * BB * HH + (size_t)(c0 + c) * HH + k];
        }

        // early i_n load for epilogue threads (independent of h)
        float in_v = 0.f;
        size_t oidx = 0;
        if (tid < 128) {
            int ec = tid >> 6, ej = tid & 63;
            oidx = ((size_t)t * BB + (c0 + ec)) * HH + s * 64 + ej;
            in_v = io[oidx];
        }
        __syncthreads();

        // partial dot products: 128 FMA/thread, h via LDS broadcast
        float pf0 = 0.f, pf1 = 0.f, pn0 = 0.f, pn1 = 0.f;
        #pragma unroll
        for (int j = 0; j < 32; j += 4) {
            float4 h0 = *(const float4*)&hst[0][w * 32 + j];
            float4 h1 = *(const float4*)&hst[1][w * 32 + j];
            pf0 = fmaf(Wf[j+0], h0.x, pf0); pn0 = fmaf(Wn[j+0], h0.x, pn0);
            pf1 = fmaf(Wf[j+0], h1.x, pf1); pn1 = fmaf(Wn[j+0], h1.x, pn1);
            pf0 = fmaf(Wf[j+1], h0.y, pf0); pn0 = fmaf(Wn[j+1], h0.y, pn0);
            pf1 = fmaf(Wf[j+1], h1.y, pf1); pn1 = fmaf(Wn[j+1], h1.y, pn1);
            pf0 = fmaf(Wf[j+2], h0.z, pf0); pn0 = fmaf(Wn[j+2], h0.z, pn0);
            pf1 = fmaf(Wf[j+2], h1.z, pf1); pn1 = fmaf(Wn[j+2], h1.z, pn1);
            pf0 = fmaf(Wf[j+3], h0.w, pf0); pn0 = fmaf(Wn[j+3], h0.w, pn0);
            pf1 = fmaf(Wf[j+3], h1.w, pf1); pn1 = fmaf(Wn[j+3], h1.w, pn1);
        }
        red[w][0][l] = pf0; red[w][1][l] = pf1;
        red[w][2][l] = pn0; red[w][3][l] = pn1;
        __syncthreads();

        // epilogue: 128 threads -> (batch ec, row ej)
        if (tid < 128) {
            int ec = tid >> 6, ej = tid & 63;
            float fs = 0.f, ns = 0.f;
            #pragma unroll
            for (int ww = 0; ww < 16; ++ww) {
                fs += red[ww][ec][ej];
                ns += red[ww][2 + ec][ej];
            }
            float fg    = 1.f / (1.f + expf(-(fs + bfv)));
            float nval  = tanhf(in_v + fg * (ns + bnv));
            float hprev = hst[ec][s * 64 + ej];
            float hnew  = nval + (1.f - fg) * (hprev - nval);
            io[oidx] = hnew;
            hbuf[(size_t)(p ^ 1) * BB * HH + (size_t)(c0 + ec) * HH + s * 64 + ej] = hnew;
        }
        __syncthreads();  // drains all waves' stores (vmcnt 0) before arrive

        // 8-WG monotonic barrier (agent scope), one line per group
        if (tid == 0) {
            __threadfence();
            __hip_atomic_fetch_add(mybar, 1u, __ATOMIC_RELEASE, __HIP_MEMORY_SCOPE_AGENT);
            unsigned int target = 8u * (unsigned int)(t + 1);
            while (__hip_atomic_load(mybar, __ATOMIC_ACQUIRE, __HIP_MEMORY_SCOPE_AGENT) < target) {
                __builtin_amdgcn_s_sleep(2);
            }
        }
        __syncthreads();
    }
}

// ---------------------------------------------------------------------------
extern "C" void kernel_launch(void* const* d_in, const int* in_sizes, int n_in,
                              void* d_out, int out_size, void* d_ws, size_t ws_size,
                              hipStream_t stream)
{
    const float* x   = (const float*)d_in[0];
    const float* Wih = (const float*)d_in[1];
    const float* Whh = (const float*)d_in[2];
    const float* bih = (const float*)d_in[3];
    const float* bhh = (const float*)d_in[4];
    float* io = (float*)d_out;

    float*        hbuf = (float*)d_ws;                                  // 2*64*512 f32 = 256 KB
    unsigned int* bar  = (unsigned int*)((char*)d_ws + 2 * BB * HH * 4); // 32 x 128B lines

    // zero ping-pong h buffer (h0 = 0) and barrier counters; re-runs every
    // launch/replay -> deterministic.
    hipMemsetAsync(d_ws, 0, 2 * BB * HH * 4 + 32 * 128, stream);

    in_gemm<<<dim3(16384), dim3(256), 0, stream>>>(x, Wih, bih, io);
    mgu_rec<<<dim3(256), dim3(1024), 0, stream>>>(Whh, bhh, io, hbuf, bar);
}

// Round 2
// 3026.637 us; speedup vs baseline: 3.4969x; 3.4969x over previous
//
#include <hip/hip_runtime.h>

#define TT 1024
#define BB 64
#define FF 256
#define HH 512

// ---------------------------------------------------------------------------
// Kernel 1: i_n = x @ W_ih^T + b_ih   ->  written into io (= d_out), later
// overwritten in-place by the recurrence with h_t.
// M = T*B = 65536, N = H = 512, K = F = 256. Tiles: 32(M) x 64(N) x 64(K).
// ---------------------------------------------------------------------------
__global__ __launch_bounds__(256) void in_gemm(
    const float* __restrict__ x, const float* __restrict__ Wih,
    const float* __restrict__ bih, float* __restrict__ io)
{
    __shared__ float xs[32][68];   // pad 68: conflict-free + 16B-aligned rows
    __shared__ float wst[64][68];  // transposed W tile: wst[k][j]

    const int bid = blockIdx.x;
    const int rb = bid >> 3, cb = bid & 7;
    const int m0 = rb * 32, n0 = cb * 64;
    const int t  = threadIdx.x;
    const int ti = t >> 4, tj = t & 15;

    float acc[2][4] = {{0.f,0.f,0.f,0.f},{0.f,0.f,0.f,0.f}};

    for (int k0 = 0; k0 < FF; k0 += 64) {
        {   // x tile: 32x64 floats, 8 per thread
            int flat = t * 8;
            int row = flat >> 6, col = flat & 63;
            const float* src = &x[(size_t)(m0 + row) * FF + k0 + col];
            float4 a = *(const float4*)&src[0];
            float4 b = *(const float4*)&src[4];
            *(float4*)&xs[row][col]     = a;
            *(float4*)&xs[row][col + 4] = b;
        }
        {   // W tile transposed: 64x64 floats, 16 per thread
            int j  = t >> 2;          // 0..63
            int kk = (t & 3) * 16;    // 0,16,32,48
            const float* src = &Wih[(size_t)(n0 + j) * FF + k0 + kk];
            #pragma unroll
            for (int q = 0; q < 4; ++q) {
                float4 v = *(const float4*)&src[q * 4];
                wst[kk + q*4 + 0][j] = v.x;
                wst[kk + q*4 + 1][j] = v.y;
                wst[kk + q*4 + 2][j] = v.z;
                wst[kk + q*4 + 3][j] = v.w;
            }
        }
        __syncthreads();
        #pragma unroll
        for (int k = 0; k < 64; k += 4) {
            float4 xa = *(const float4*)&xs[ti][k];
            float4 xb = *(const float4*)&xs[ti + 16][k];
            #pragma unroll
            for (int q = 0; q < 4; ++q) {
                float4 wv = *(const float4*)&wst[k + q][tj * 4];
                float xav = (&xa.x)[q], xbv = (&xb.x)[q];
                acc[0][0] = fmaf(xav, wv.x, acc[0][0]);
                acc[0][1] = fmaf(xav, wv.y, acc[0][1]);
                acc[0][2] = fmaf(xav, wv.z, acc[0][2]);
                acc[0][3] = fmaf(xav, wv.w, acc[0][3]);
                acc[1][0] = fmaf(xbv, wv.x, acc[1][0]);
                acc[1][1] = fmaf(xbv, wv.y, acc[1][1]);
                acc[1][2] = fmaf(xbv, wv.z, acc[1][2]);
                acc[1][3] = fmaf(xbv, wv.w, acc[1][3]);
            }
        }
        __syncthreads();
    }

    float4 bv = *(const float4*)&bih[n0 + tj * 4];
    float4 r0 = make_float4(acc[0][0]+bv.x, acc[0][1]+bv.y, acc[0][2]+bv.z, acc[0][3]+bv.w);
    float4 r1 = make_float4(acc[1][0]+bv.x, acc[1][1]+bv.y, acc[1][2]+bv.z, acc[1][3]+bv.w);
    *(float4*)&io[(size_t)(m0 + ti)      * HH + n0 + tj * 4] = r0;
    *(float4*)&io[(size_t)(m0 + ti + 16) * HH + n0 + tj * 4] = r1;
}

// ---------------------------------------------------------------------------
// Kernel 2: persistent recurrence. Same decomposition as round 1:
// 256 WGs = 8 row-slices (s) x 32 batch-groups (g, 2 batches each); W_hh
// slice (128 rows x 512) persistent in registers (64 VGPR/thread).
//
// ROUND-2 CHANGES (fence-free sync):
//  * h exchange + barrier counter use RELAXED AGENT atomics only. These
//    compile to global ops with sc1 (coherence-point access, L2 bypass) and
//    emit NO buffer_wbl2 / buffer_inv — round 1's per-step device fences
//    were invalidating+writing-back L2 on all 256 WGs every step (~9 us/step
//    of stall). Ordering: __syncthreads() drains each wave's vmcnt before
//    the counter bump, so h-stores are at L3 before the flag moves.
//  * W as float4[8] arrays; inner loop chunked with sched_barrier(0) so the
//    scheduler can't hoist all 16 h ds_reads (that hoisting blew register
//    pressure past 128 and evicted W in round 1 -> VGPR_Count=52).
// ---------------------------------------------------------------------------
__global__ __launch_bounds__(1024, 4) void mgu_rec(
    const float* __restrict__ Whh, const float* __restrict__ bhh,
    float* __restrict__ io, float* __restrict__ hbuf,
    unsigned int* __restrict__ bar)
{
    const int bid = blockIdx.x;
    const int s   = bid >> 5;     // row slice 0..7
    const int g   = bid & 31;     // batch group 0..31
    const int c0  = g * 2;        // first batch of this group
    const int tid = threadIdx.x;
    const int w   = tid >> 6;     // wave 0..15 -> k-slice
    const int l   = tid & 63;     // lane -> row offset within slice

    __shared__ float hst[2][HH];      // staged h for the 2 batches (4 KB)
    __shared__ float red[16][4][64];  // per-wave partials (16 KB)

    // --- load persistent W registers: 16 float4 tuples = 64 VGPRs ---
    float4 Wf4[8], Wn4[8];
    {
        const float* pf = &Whh[(size_t)(s * 64 + l) * HH + w * 32];
        const float* pn = &Whh[(size_t)(512 + s * 64 + l) * HH + w * 32];
        #pragma unroll
        for (int q = 0; q < 8; ++q) {
            Wf4[q] = *(const float4*)&pf[q * 4];
            Wn4[q] = *(const float4*)&pn[q * 4];
        }
    }

    float bfv = 0.f, bnv = 0.f;
    if (tid < 128) {
        int ej = tid & 63;
        bfv = bhh[s * 64 + ej];
        bnv = bhh[512 + s * 64 + ej];
    }

    unsigned int* mybar = &bar[g * 32];  // 128B-spaced line per group

    for (int t = 0; t < TT; ++t) {
        const int p = t & 1;

        // stage h (2 batches x 512) into LDS via relaxed agent loads (sc1:
        // reads the coherence point, no stale-L2 hazard, no cache maint.)
        {
            int c = tid >> 9;       // 0..1
            int k = tid & 511;
            const float* src = &hbuf[p * BB * HH + (c0 + c) * HH + k];
            hst[c][k] = __hip_atomic_load(src, __ATOMIC_RELAXED,
                                          __HIP_MEMORY_SCOPE_AGENT);
        }

        // early i_n load for epilogue threads (independent of h; normal
        // cached load — io was written by in_gemm before this kernel)
        float in_v = 0.f;
        size_t oidx = 0;
        if (tid < 128) {
            int ec = tid >> 6, ej = tid & 63;
            oidx = ((size_t)t * BB + (c0 + ec)) * HH + s * 64 + ej;
            in_v = io[oidx];
        }
        __syncthreads();

        // partial dot products: 128 FMA/thread, h via LDS broadcast.
        // sched_barrier(0) per 4-wide chunk: caps live h-vectors at 2,
        // keeping total pressure ~90 VGPR so W stays resident.
        float pf0 = 0.f, pf1 = 0.f, pn0 = 0.f, pn1 = 0.f;
        #pragma unroll
        for (int q = 0; q < 8; ++q) {
            float4 h0 = *(const float4*)&hst[0][w * 32 + q * 4];
            float4 h1 = *(const float4*)&hst[1][w * 32 + q * 4];
            pf0 = fmaf(Wf4[q].x, h0.x, pf0); pn0 = fmaf(Wn4[q].x, h0.x, pn0);
            pf1 = fmaf(Wf4[q].x, h1.x, pf1); pn1 = fmaf(Wn4[q].x, h1.x, pn1);
            pf0 = fmaf(Wf4[q].y, h0.y, pf0); pn0 = fmaf(Wn4[q].y, h0.y, pn0);
            pf1 = fmaf(Wf4[q].y, h1.y, pf1); pn1 = fmaf(Wn4[q].y, h1.y, pn1);
            pf0 = fmaf(Wf4[q].z, h0.z, pf0); pn0 = fmaf(Wn4[q].z, h0.z, pn0);
            pf1 = fmaf(Wf4[q].z, h1.z, pf1); pn1 = fmaf(Wn4[q].z, h1.z, pn1);
            pf0 = fmaf(Wf4[q].w, h0.w, pf0); pn0 = fmaf(Wn4[q].w, h0.w, pn0);
            pf1 = fmaf(Wf4[q].w, h1.w, pf1); pn1 = fmaf(Wn4[q].w, h1.w, pn1);
            __builtin_amdgcn_sched_barrier(0);
        }
        red[w][0][l] = pf0; red[w][1][l] = pf1;
        red[w][2][l] = pn0; red[w][3][l] = pn1;
        __syncthreads();

        // epilogue: 128 threads -> (batch ec, row ej)
        if (tid < 128) {
            int ec = tid >> 6, ej = tid & 63;
            float fs = 0.f, ns = 0.f;
            #pragma unroll
            for (int ww = 0; ww < 16; ++ww) {
                fs += red[ww][ec][ej];
                ns += red[ww][2 + ec][ej];
            }
            float fg    = 1.f / (1.f + expf(-(fs + bfv)));
            float nval  = tanhf(in_v + fg * (ns + bnv));
            float hprev = hst[ec][s * 64 + ej];
            float hnew  = nval + (1.f - fg) * (hprev - nval);
            io[oidx] = hnew;  // normal store (read only by harness)
            // h for next step: relaxed agent store -> visible at L3 once
            // this wave's vmcnt drains (at the next __syncthreads)
            float* dst = &hbuf[(p ^ 1) * BB * HH + (c0 + ec) * HH + s * 64 + ej];
            __hip_atomic_store(dst, hnew, __ATOMIC_RELAXED,
                               __HIP_MEMORY_SCOPE_AGENT);
        }
        __syncthreads();  // all waves drain vmcnt(0) -> h stores at L3

        // 8-WG monotonic barrier: relaxed agent RMW + relaxed spin.
        // No fences -> no L2 writeback/invalidate anywhere in the loop.
        if (tid == 0) {
            __hip_atomic_fetch_add(mybar, 1u, __ATOMIC_RELAXED,
                                   __HIP_MEMORY_SCOPE_AGENT);
            unsigned int target = 8u * (unsigned int)(t + 1);
            while (__hip_atomic_load(mybar, __ATOMIC_RELAXED,
                                     __HIP_MEMORY_SCOPE_AGENT) < target) {
                __builtin_amdgcn_s_sleep(1);
            }
        }
        __syncthreads();
    }
}

// ---------------------------------------------------------------------------
extern "C" void kernel_launch(void* const* d_in, const int* in_sizes, int n_in,
                              void* d_out, int out_size, void* d_ws, size_t ws_size,
                              hipStream_t stream)
{
    const float* x   = (const float*)d_in[0];
    const float* Wih = (const float*)d_in[1];
    const float* Whh = (const float*)d_in[2];
    const float* bih = (const float*)d_in[3];
    const float* bhh = (const float*)d_in[4];
    float* io = (float*)d_out;

    float*        hbuf = (float*)d_ws;                                   // 2*64*512 f32 = 256 KB
    unsigned int* bar  = (unsigned int*)((char*)d_ws + 2 * BB * HH * 4); // 32 x 128B lines

    // zero ping-pong h buffer (h0 = 0) and barrier counters; re-runs every
    // launch/replay -> deterministic.
    hipMemsetAsync(d_ws, 0, 2 * BB * HH * 4 + 32 * 128, stream);

    in_gemm<<<dim3(16384), dim3(256), 0, stream>>>(x, Wih, bih, io);
    mgu_rec<<<dim3(256), dim3(1024), 0, stream>>>(Whh, bhh, io, hbuf, bar);
}